// Round 1
// baseline (10243.497 us; speedup 1.0000x reference)
//
#include <hip/hip_runtime.h>
#include <hip/hip_bf16.h>

// Problem constants (B,T,F,D,O,L) = (64, 512, 20, 1024, 1095, 3)
#define B_ 64
#define T_ 512
#define F_ 20
#define D_ 1024
#define O_ 1095
#define L_ 3

// ---------------------------------------------------------------------------
// FC1: h[t*B+b, d] = sum_f x[b,t,f] * W1[f,d] + b1[d]   (time-major output)
// ---------------------------------------------------------------------------
__global__ __launch_bounds__(256) void fc1_kernel(
    const float* __restrict__ x, const float* __restrict__ W1,
    const float* __restrict__ b1, float* __restrict__ h)
{
    int idx = blockIdx.x * 256 + threadIdx.x;   // over T*B*D = 33,554,432
    int d  = idx & (D_ - 1);
    int tb = idx >> 10;          // t*B + b
    int b  = tb & (B_ - 1);
    int t  = tb >> 6;
    const float* xr = x + ((size_t)b * T_ + t) * F_;
    float s = b1[d];
#pragma unroll
    for (int f = 0; f < F_; ++f) s += xr[f] * W1[f * D_ + d];
    h[idx] = s;
}

// ---------------------------------------------------------------------------
// Tiled fp32 GEMM: C[M,N] = A[M,K] @ Bm[K,N] (+bias) (+row remap for final)
// 64x64 tile, BK=16, 256 threads, 4x4 microtile.
// M must be a multiple of 64 and K a multiple of 16 (true for all our calls).
// NV4: N % 64 == 0 -> vector B loads, no col guards.
// remap: output row = (m % Bb) * Tt + (m / Bb)   (time-major -> batch-major)
// ---------------------------------------------------------------------------
template<bool NV4>
__global__ __launch_bounds__(256) void gemm_kernel(
    const float* __restrict__ A, const float* __restrict__ Bm,
    float* __restrict__ C, int M, int N, int K,
    const float* __restrict__ bias, int remap, int Tt, int Bb)
{
    __shared__ __align__(16) float As[16][64];   // [k][row]
    __shared__ __align__(16) float Bs[16][64];   // [k][col]

    const int tid = threadIdx.x;
    const int tx = tid & 15;          // col group
    const int ty = tid >> 4;          // row group
    const int rowBase = blockIdx.y * 64;
    const int colBase = blockIdx.x * 64;

    // A staging map: 64 rows x 16 k -> one float4 per thread
    const int arow = tid >> 2;              // 0..63
    const int akc  = (tid & 3) << 2;        // 0,4,8,12

    float acc[4][4] = {};

    for (int k0 = 0; k0 < K; k0 += 16) {
        // stage A (transposed into [k][row])
        float4 av = *(const float4*)(A + (size_t)(rowBase + arow) * K + k0 + akc);
        As[akc + 0][arow] = av.x;
        As[akc + 1][arow] = av.y;
        As[akc + 2][arow] = av.z;
        As[akc + 3][arow] = av.w;
        // stage B: 16 k-rows x 64 cols -> krow = ty, cols = tx*4..tx*4+3
        if (NV4) {
            float4 bv = *(const float4*)(Bm + (size_t)(k0 + ty) * N + colBase + (tx << 2));
            *(float4*)&Bs[ty][tx << 2] = bv;
        } else {
#pragma unroll
            for (int j = 0; j < 4; ++j) {
                int col = colBase + (tx << 2) + j;
                Bs[ty][(tx << 2) + j] = (col < N) ? Bm[(size_t)(k0 + ty) * N + col] : 0.f;
            }
        }
        __syncthreads();

#pragma unroll
        for (int k = 0; k < 16; ++k) {
            float4 a4 = *(const float4*)&As[k][ty << 2];
            float4 b4 = *(const float4*)&Bs[k][tx << 2];
            float a[4] = {a4.x, a4.y, a4.z, a4.w};
            float b[4] = {b4.x, b4.y, b4.z, b4.w};
#pragma unroll
            for (int i = 0; i < 4; ++i)
#pragma unroll
                for (int j = 0; j < 4; ++j)
                    acc[i][j] = fmaf(a[i], b[j], acc[i][j]);
        }
        __syncthreads();
    }

#pragma unroll
    for (int i = 0; i < 4; ++i) {
        int m = rowBase + (ty << 2) + i;
        size_t orow = remap ? ((size_t)(m % Bb) * Tt + (m / Bb)) : (size_t)m;
#pragma unroll
        for (int j = 0; j < 4; ++j) {
            int col = colBase + (tx << 2) + j;
            if (NV4 || col < N) {
                float v = acc[i][j];
                if (bias) v += bias[col];
                C[orow * N + col] = v;
            }
        }
    }
}

// ---------------------------------------------------------------------------
// SRU elementwise scan. One thread per (b,d) channel; U is a chunk buffer
// whose row 0 corresponds to global timestep t0. h updated in place.
// ---------------------------------------------------------------------------
__global__ __launch_bounds__(256) void sru_scan(
    const float* __restrict__ U, float* __restrict__ h,
    const float* __restrict__ v, const float* __restrict__ bvec,
    float* __restrict__ carry, float* __restrict__ cfin,
    int t0, int t1)
{
    int idx = blockIdx.x * 256 + threadIdx.x;   // 0..B*D-1
    int d = idx & (D_ - 1);
    int b = idx >> 10;

    float vf = v[d],      vr = v[D_ + d];
    float bf = bvec[d],   br = bvec[D_ + d];
    float c = (t0 == 0) ? 0.f : carry[idx];

    const float* Up = U + (size_t)b * (3 * D_) + d;     // chunk-relative t
    float* hp = h + (size_t)t0 * (B_ * D_) + idx;

    for (int t = t0; t < t1; ++t) {
        float u0 = Up[0];
        float u1 = Up[D_];
        float u2 = Up[2 * D_];
        float xt = *hp;
        float f = 1.f / (1.f + expf(-(u1 + vf * c + bf)));
        c = f * c + (1.f - f) * u0;
        float r = 1.f / (1.f + expf(-(u2 + vr * c + br)));
        *hp = r * c + (1.f - r) * xt;
        Up += (size_t)B_ * 3 * D_;
        hp += (size_t)B_ * D_;
    }
    carry[idx] = c;
    if (cfin) cfin[idx] = c;   // (b,d) layout == reference c_fin layout
}

// ---------------------------------------------------------------------------
extern "C" void kernel_launch(void* const* d_in, const int* in_sizes, int n_in,
                              void* d_out, int out_size, void* d_ws, size_t ws_size,
                              hipStream_t stream)
{
    const float* x     = (const float*)d_in[0];
    // d_in[1] is c (ignored by the reference module)
    const float* W1    = (const float*)d_in[2];
    const float* b1    = (const float*)d_in[3];
    const float* sru_W = (const float*)d_in[4];
    const float* sru_v = (const float*)d_in[5];
    const float* sru_b = (const float*)d_in[6];
    const float* W3    = (const float*)d_in[7];
    const float* b3    = (const float*)d_in[8];

    float* y    = (float*)d_out;                       // (B*T, O) batch-major
    float* cfin = y + (size_t)(B_ * T_) * O_;          // (L, B, D)

    // Workspace layout: h (T*B*D f32) | carry (B*D f32) | U chunk buffer
    char*  ws = (char*)d_ws;
    float* h  = (float*)ws;
    size_t h_bytes = (size_t)T_ * B_ * D_ * sizeof(float);          // 128 MiB
    float* carry = (float*)(ws + h_bytes);
    size_t carry_bytes = (size_t)B_ * D_ * sizeof(float);
    float* Ubuf = (float*)(ws + h_bytes + carry_bytes);

    size_t perT  = (size_t)B_ * 3 * D_ * sizeof(float);             // 768 KiB / timestep
    size_t avail = (ws_size > h_bytes + carry_bytes) ? ws_size - h_bytes - carry_bytes : 0;
    int chunkT = (int)(avail / perT);
    if (chunkT < 1)   chunkT = 1;
    if (chunkT > T_)  chunkT = T_;

    // 1) FC1 -> h, time-major
    fc1_kernel<<<(T_ * B_ * D_) / 256, 256, 0, stream>>>(x, W1, b1, h);

    // 2) SRU layers
    for (int l = 0; l < L_; ++l) {
        const float* Wl = sru_W + (size_t)l * D_ * 3 * D_;
        const float* vl = sru_v + (size_t)l * 2 * D_;
        const float* bl = sru_b + (size_t)l * 2 * D_;
        for (int t0 = 0; t0 < T_; t0 += chunkT) {
            int t1 = (t0 + chunkT > T_) ? T_ : (t0 + chunkT);
            int rows = (t1 - t0) * B_;
            dim3 g(3 * D_ / 64, rows / 64);
            gemm_kernel<true><<<g, 256, 0, stream>>>(
                h + (size_t)t0 * B_ * D_, Wl, Ubuf, rows, 3 * D_, D_,
                nullptr, 0, 0, 0);
            sru_scan<<<(B_ * D_) / 256, 256, 0, stream>>>(
                Ubuf, h, vl, bl, carry,
                (t1 == T_) ? (cfin + (size_t)l * B_ * D_) : nullptr,
                t0, t1);
        }
    }

    // 3) Final: y[b*T+t, :] = h[t*B+b, :] @ W3 + b3   (row remap, N=1095 unaligned)
    dim3 gf((O_ + 63) / 64, (B_ * T_) / 64);
    gemm_kernel<false><<<gf, 256, 0, stream>>>(
        h, W3, y, B_ * T_, O_, D_, b3, 1, T_, B_);
}

// Round 2
// 2387.343 us; speedup vs baseline: 4.2908x; 4.2908x over previous
//
#include <hip/hip_runtime.h>
#include <hip/hip_bf16.h>

// Problem constants (B,T,F,D,O,L) = (64, 512, 20, 1024, 1095, 3)
#define B_ 64
#define T_ 512
#define F_ 20
#define D_ 1024
#define O_ 1095
#define L_ 3
#define OPAD 1152   // O_ padded to multiple of 128 for the MFMA tile

typedef __attribute__((ext_vector_type(8))) short bf16x8;   // 8 bf16 = 4 VGPRs
typedef __attribute__((ext_vector_type(4))) float f32x4;

// async global->LDS, 16 bytes/lane. LDS dst must be wave-uniform base;
// HW writes base + lane*16 (guide §5 caveat).
__device__ __forceinline__ void async16(const void* g, void* l) {
    __builtin_amdgcn_global_load_lds(
        (const __attribute__((address_space(1))) unsigned int*)g,
        (__attribute__((address_space(3))) unsigned int*)l, 16, 0, 0);
}

// ---------------------------------------------------------------------------
// FC1: h[t*B+b, d] = sum_f x[b,t,f] * W1[f,d] + b1[d]  -> bf16, time-major
// ---------------------------------------------------------------------------
__global__ __launch_bounds__(256) void fc1_kernel(
    const float* __restrict__ x, const float* __restrict__ W1,
    const float* __restrict__ b1, __hip_bfloat16* __restrict__ h)
{
    int idx = blockIdx.x * 256 + threadIdx.x;   // over T*B*D
    int d  = idx & (D_ - 1);
    int tb = idx >> 10;          // t*B + b
    int b  = tb & (B_ - 1);
    int t  = tb >> 6;
    const float* xr = x + ((size_t)b * T_ + t) * F_;
    float s = b1[d];
#pragma unroll
    for (int f = 0; f < F_; ++f) s += xr[f] * W1[f * D_ + d];
    h[idx] = __float2bfloat16(s);
}

// ---------------------------------------------------------------------------
// Tiled transpose+cast: in fp32 (K x N) -> out bf16 (Npad x K), zero-pad rows
// ---------------------------------------------------------------------------
__global__ __launch_bounds__(256) void transpose_cast(
    const float* __restrict__ in, __hip_bfloat16* __restrict__ out,
    int K, int N, int Npad)
{
    __shared__ float tile[32][33];
    int k0 = blockIdx.x * 32;
    int n0 = blockIdx.y * 32;
    int tx = threadIdx.x & 31, ty = threadIdx.x >> 5;   // ty 0..7
#pragma unroll
    for (int r = 0; r < 4; ++r) {
        int n = n0 + tx;
        int k = k0 + ty + r * 8;
        tile[ty + r * 8][tx] = (n < N) ? in[(size_t)k * N + n] : 0.f;
    }
    __syncthreads();
#pragma unroll
    for (int r = 0; r < 4; ++r) {
        int nn = n0 + ty + r * 8;
        out[(size_t)nn * K + k0 + tx] = __float2bfloat16(tile[tx][ty + r * 8]);
    }
}

// ---------------------------------------------------------------------------
// m97-style MFMA GEMM: C[M,N] = A[M,K] @ Bt[N,K]^T  (bf16 in, fp32 out)
// 128x128 tile, BK=32, 256 threads (4 waves, 2x2 wave grid, 4x4 MFMA each).
// M, K multiples of 128/32. Grid.x covers Npad/128; store guards n < Nreal.
// REMAP: output row (m = t*B+b) -> b*T + t  (time-major -> batch-major).
// ---------------------------------------------------------------------------
template<bool GUARD_N, bool REMAP>
__global__ __launch_bounds__(256) void mfma_gemm(
    const __hip_bfloat16* __restrict__ A,
    const __hip_bfloat16* __restrict__ Bt,
    float* __restrict__ C,
    int K, int ldc, int Nreal,
    const float* __restrict__ bias)
{
    __shared__ __align__(16) char smem[16384];
    char* As = smem;            // 128 rows x 32 k x bf16 = 8192 B
    char* Bs = smem + 8192;

    const int tid  = threadIdx.x;
    const int lane = tid & 63;
    const int w    = tid >> 6;

    const int tileM = blockIdx.y * 128;
    const int tileN = blockIdx.x * 128;

    // staging map: flat 16B-chunk f -> row f>>2, col (f&3)*8 ; f0=tid, f1=tid+256
    const int r0 = tid >> 2, c0 = (tid & 3) * 8;
    const __hip_bfloat16* pA0 = A  + (size_t)(tileM + r0) * K + c0;
    const __hip_bfloat16* pA1 = A  + (size_t)(tileM + r0 + 64) * K + c0;
    const __hip_bfloat16* pB0 = Bt + (size_t)(tileN + r0) * K + c0;
    const __hip_bfloat16* pB1 = Bt + (size_t)(tileN + r0 + 64) * K + c0;

    const int wb = w * 1024;    // wave-uniform LDS byte offset (64 lanes * 16 B)

    // wave sub-tile
    const int wm = (w & 1) * 64;
    const int wn = (w >> 1) * 64;
    const int lr = lane & 15;
    const int lkB = (lane >> 4) * 16;   // k byte offset (8 bf16)

    f32x4 acc[4][4] = {};

    for (int k0 = 0; k0 < K; k0 += 32) {
        async16(pA0 + k0, As + wb);
        async16(pA1 + k0, As + 4096 + wb);
        async16(pB0 + k0, Bs + wb);
        async16(pB1 + k0, Bs + 4096 + wb);
        __syncthreads();   // drains vmcnt -> LDS visible

        bf16x8 a_frag[4], b_frag[4];
#pragma unroll
        for (int i = 0; i < 4; ++i)
            a_frag[i] = *(const bf16x8*)(As + (wm + i * 16 + lr) * 64 + lkB);
#pragma unroll
        for (int j = 0; j < 4; ++j)
            b_frag[j] = *(const bf16x8*)(Bs + (wn + j * 16 + lr) * 64 + lkB);

#pragma unroll
        for (int i = 0; i < 4; ++i)
#pragma unroll
            for (int j = 0; j < 4; ++j)
                acc[i][j] = __builtin_amdgcn_mfma_f32_16x16x32_bf16(
                    a_frag[i], b_frag[j], acc[i][j], 0, 0, 0);
        __syncthreads();   // protect LDS before next stage
    }

    // epilogue: C/D layout col=lane&15, row=(lane>>4)*4+reg
    const int rquad = (lane >> 4) * 4;
#pragma unroll
    for (int i = 0; i < 4; ++i) {
#pragma unroll
        for (int r = 0; r < 4; ++r) {
            int m = tileM + wm + i * 16 + rquad + r;
            size_t orow = REMAP ? ((size_t)(m & (B_ - 1)) * T_ + (m >> 6)) : (size_t)m;
            float* crow = C + orow * ldc;
#pragma unroll
            for (int j = 0; j < 4; ++j) {
                int n = tileN + wn + j * 16 + lr;
                if (!GUARD_N || n < Nreal) {
                    float v = acc[i][j][r];
                    if (bias) v += bias[n];
                    crow[n] = v;
                }
            }
        }
    }
}

// ---------------------------------------------------------------------------
// SRU elementwise scan. One thread per (b,d); U fp32 chunk (row 0 == t0),
// h bf16 updated in place; carry fp32.
// ---------------------------------------------------------------------------
__global__ __launch_bounds__(256) void sru_scan(
    const float* __restrict__ U, __hip_bfloat16* __restrict__ h,
    const float* __restrict__ v, const float* __restrict__ bvec,
    float* __restrict__ carry, float* __restrict__ cfin,
    int t0, int t1)
{
    int idx = blockIdx.x * 256 + threadIdx.x;   // 0..B*D-1
    int d = idx & (D_ - 1);

    float vf = v[d],      vr = v[D_ + d];
    float bf = bvec[d],   br = bvec[D_ + d];
    float c = (t0 == 0) ? 0.f : carry[idx];

    int b = idx >> 10;
    const float* Up = U + (size_t)b * (3 * D_) + d;
    __hip_bfloat16* hp = h + (size_t)t0 * (B_ * D_) + idx;

    for (int t = t0; t < t1; ++t) {
        float u0 = Up[0];
        float u1 = Up[D_];
        float u2 = Up[2 * D_];
        float xt = __bfloat162float(*hp);
        float f = 1.f / (1.f + __expf(-(u1 + vf * c + bf)));
        c = f * c + (1.f - f) * u0;
        float r = 1.f / (1.f + __expf(-(u2 + vr * c + br)));
        *hp = __float2bfloat16(r * c + (1.f - r) * xt);
        Up += (size_t)B_ * 3 * D_;
        hp += (size_t)B_ * D_;
    }
    carry[idx] = c;
    if (cfin) cfin[idx] = c;
}

// ---------------------------------------------------------------------------
extern "C" void kernel_launch(void* const* d_in, const int* in_sizes, int n_in,
                              void* d_out, int out_size, void* d_ws, size_t ws_size,
                              hipStream_t stream)
{
    const float* x     = (const float*)d_in[0];
    const float* W1    = (const float*)d_in[2];
    const float* b1    = (const float*)d_in[3];
    const float* sru_W = (const float*)d_in[4];
    const float* sru_v = (const float*)d_in[5];
    const float* sru_b = (const float*)d_in[6];
    const float* W3    = (const float*)d_in[7];
    const float* b3    = (const float*)d_in[8];

    float* y    = (float*)d_out;                       // (B*T, O) batch-major
    float* cfin = y + (size_t)(B_ * T_) * O_;          // (L, B, D)

    // Workspace layout
    char* ws = (char*)d_ws;
    size_t off = 0;
    __hip_bfloat16* h = (__hip_bfloat16*)(ws + off);
    off += (size_t)T_ * B_ * D_ * sizeof(__hip_bfloat16);           // 64 MiB
    float* carry = (float*)(ws + off);
    off += (size_t)B_ * D_ * sizeof(float);
    __hip_bfloat16* Wt = (__hip_bfloat16*)(ws + off);               // L x (3D x D)
    off += (size_t)L_ * 3 * D_ * D_ * sizeof(__hip_bfloat16);
    __hip_bfloat16* Wt3 = (__hip_bfloat16*)(ws + off);              // OPAD x D
    off += (size_t)OPAD * D_ * sizeof(__hip_bfloat16);
    float* Ubuf = (float*)(ws + off);

    size_t perT  = (size_t)B_ * 3 * D_ * sizeof(float);             // 768 KiB / t
    size_t avail = (ws_size > off) ? ws_size - off : 0;
    int chunkT = (int)(avail / perT) & ~1;                          // even (M%128==0)
    if (chunkT < 2)   chunkT = 2;
    if (chunkT > T_)  chunkT = T_;

    // 0) weight transpose+cast (every call; no static state allowed)
    for (int l = 0; l < L_; ++l) {
        dim3 gt(D_ / 32, (3 * D_) / 32);
        transpose_cast<<<gt, 256, 0, stream>>>(
            sru_W + (size_t)l * D_ * 3 * D_, Wt + (size_t)l * 3 * D_ * D_,
            D_, 3 * D_, 3 * D_);
    }
    {
        dim3 gt(D_ / 32, OPAD / 32);
        transpose_cast<<<gt, 256, 0, stream>>>(W3, Wt3, D_, O_, OPAD);
    }

    // 1) FC1 -> h (bf16, time-major)
    fc1_kernel<<<(T_ * B_ * D_) / 256, 256, 0, stream>>>(x, W1, b1, h);

    // 2) SRU layers: bulk U GEMM (chunked) + elementwise scan
    for (int l = 0; l < L_; ++l) {
        const __hip_bfloat16* Wl = Wt + (size_t)l * 3 * D_ * D_;
        const float* vl = sru_v + (size_t)l * 2 * D_;
        const float* bl = sru_b + (size_t)l * 2 * D_;
        for (int t0 = 0; t0 < T_; t0 += chunkT) {
            int t1 = (t0 + chunkT > T_) ? T_ : (t0 + chunkT);
            int rows = (t1 - t0) * B_;
            dim3 g((3 * D_) / 128, rows / 128);
            mfma_gemm<false, false><<<g, 256, 0, stream>>>(
                h + (size_t)t0 * B_ * D_, Wl, Ubuf,
                D_, 3 * D_, 3 * D_, nullptr);
            sru_scan<<<(B_ * D_) / 256, 256, 0, stream>>>(
                Ubuf, h, vl, bl, carry,
                (t1 == T_) ? (cfin + (size_t)l * B_ * D_) : nullptr,
                t0, t1);
        }
    }

    // 3) Final: y[b*T+t, :] = h[t*B+b, :] @ W3 + b3  (N guarded to 1095, remap)
    dim3 gf(OPAD / 128, (B_ * T_) / 128);
    mfma_gemm<true, true><<<gf, 256, 0, stream>>>(
        h, Wt3, y, D_, O_, O_, b3);
}

// Round 3
// 1822.604 us; speedup vs baseline: 5.6203x; 1.3099x over previous
//
#include <hip/hip_runtime.h>
#include <hip/hip_bf16.h>

// Problem constants (B,T,F,D,O,L) = (64, 512, 20, 1024, 1095, 3)
#define B_ 64
#define T_ 512
#define F_ 20
#define D_ 1024
#define O_ 1095
#define L_ 3
#define OPAD 1152   // O_ padded to multiple of 128 for the MFMA tile

typedef __attribute__((ext_vector_type(8))) short bf16x8;   // 8 bf16 = 4 VGPRs
typedef __attribute__((ext_vector_type(4))) float f32x4;

// async global->LDS, 16 bytes/lane. LDS dst must be wave-uniform base;
// HW writes base + lane*16 (guide §5 caveat).
__device__ __forceinline__ void async16(const void* g, void* l) {
    __builtin_amdgcn_global_load_lds(
        (const __attribute__((address_space(1))) unsigned int*)g,
        (__attribute__((address_space(3))) unsigned int*)l, 16, 0, 0);
}

// ---------------------------------------------------------------------------
// FC1: h[t*B+b, d] = sum_f x[b,t,f] * W1[f,d] + b1[d]  -> bf16, time-major
// ---------------------------------------------------------------------------
__global__ __launch_bounds__(256) void fc1_kernel(
    const float* __restrict__ x, const float* __restrict__ W1,
    const float* __restrict__ b1, __hip_bfloat16* __restrict__ h)
{
    int idx = blockIdx.x * 256 + threadIdx.x;   // over T*B*D
    int d  = idx & (D_ - 1);
    int tb = idx >> 10;          // t*B + b
    int b  = tb & (B_ - 1);
    int t  = tb >> 6;
    const float* xr = x + ((size_t)b * T_ + t) * F_;
    float s = b1[d];
#pragma unroll
    for (int f = 0; f < F_; ++f) s += xr[f] * W1[f * D_ + d];
    h[idx] = __float2bfloat16(s);
}

// ---------------------------------------------------------------------------
// Tiled transpose+cast: in fp32 (K x N) -> out bf16 (Npad x K), zero-pad rows
// ---------------------------------------------------------------------------
__global__ __launch_bounds__(256) void transpose_cast(
    const float* __restrict__ in, __hip_bfloat16* __restrict__ out,
    int K, int N, int Npad)
{
    __shared__ float tile[32][33];
    int k0 = blockIdx.x * 32;
    int n0 = blockIdx.y * 32;
    int tx = threadIdx.x & 31, ty = threadIdx.x >> 5;   // ty 0..7
#pragma unroll
    for (int r = 0; r < 4; ++r) {
        int n = n0 + tx;
        int k = k0 + ty + r * 8;
        tile[ty + r * 8][tx] = (n < N) ? in[(size_t)k * N + n] : 0.f;
    }
    __syncthreads();
#pragma unroll
    for (int r = 0; r < 4; ++r) {
        int nn = n0 + ty + r * 8;
        out[(size_t)nn * K + k0 + tx] = __float2bfloat16(tile[tx][ty + r * 8]);
    }
}

// ---------------------------------------------------------------------------
// m97-style MFMA GEMM: C[M,N] = A[M,K] @ Bt[N,K]^T  (bf16 in, fp32 out)
// 128x128 tile, BK=32, 256 threads (4 waves, 2x2 wave grid, 4x4 MFMA each).
// ---------------------------------------------------------------------------
template<bool GUARD_N, bool REMAP>
__global__ __launch_bounds__(256) void mfma_gemm(
    const __hip_bfloat16* __restrict__ A,
    const __hip_bfloat16* __restrict__ Bt,
    float* __restrict__ C,
    int K, int ldc, int Nreal,
    const float* __restrict__ bias)
{
    __shared__ __align__(16) char smem[16384];
    char* As = smem;            // 128 rows x 32 k x bf16 = 8192 B
    char* Bs = smem + 8192;

    const int tid  = threadIdx.x;
    const int lane = tid & 63;
    const int w    = tid >> 6;

    const int tileM = blockIdx.y * 128;
    const int tileN = blockIdx.x * 128;

    const int r0 = tid >> 2, c0 = (tid & 3) * 8;
    const __hip_bfloat16* pA0 = A  + (size_t)(tileM + r0) * K + c0;
    const __hip_bfloat16* pA1 = A  + (size_t)(tileM + r0 + 64) * K + c0;
    const __hip_bfloat16* pB0 = Bt + (size_t)(tileN + r0) * K + c0;
    const __hip_bfloat16* pB1 = Bt + (size_t)(tileN + r0 + 64) * K + c0;

    const int wb = w * 1024;    // wave-uniform LDS byte offset

    const int wm = (w & 1) * 64;
    const int wn = (w >> 1) * 64;
    const int lr = lane & 15;
    const int lkB = (lane >> 4) * 16;

    f32x4 acc[4][4] = {};

    for (int k0 = 0; k0 < K; k0 += 32) {
        async16(pA0 + k0, As + wb);
        async16(pA1 + k0, As + 4096 + wb);
        async16(pB0 + k0, Bs + wb);
        async16(pB1 + k0, Bs + 4096 + wb);
        __syncthreads();

        bf16x8 a_frag[4], b_frag[4];
#pragma unroll
        for (int i = 0; i < 4; ++i)
            a_frag[i] = *(const bf16x8*)(As + (wm + i * 16 + lr) * 64 + lkB);
#pragma unroll
        for (int j = 0; j < 4; ++j)
            b_frag[j] = *(const bf16x8*)(Bs + (wn + j * 16 + lr) * 64 + lkB);

#pragma unroll
        for (int i = 0; i < 4; ++i)
#pragma unroll
            for (int j = 0; j < 4; ++j)
                acc[i][j] = __builtin_amdgcn_mfma_f32_16x16x32_bf16(
                    a_frag[i], b_frag[j], acc[i][j], 0, 0, 0);
        __syncthreads();
    }

    const int rquad = (lane >> 4) * 4;
#pragma unroll
    for (int i = 0; i < 4; ++i) {
#pragma unroll
        for (int r = 0; r < 4; ++r) {
            int m = tileM + wm + i * 16 + rquad + r;
            size_t orow = REMAP ? ((size_t)(m & (B_ - 1)) * T_ + (m >> 6)) : (size_t)m;
            float* crow = C + orow * ldc;
#pragma unroll
            for (int j = 0; j < 4; ++j) {
                int n = tileN + wn + j * 16 + lr;
                if (!GUARD_N || n < Nreal) {
                    float v = acc[i][j][r];
                    if (bias) v += bias[n];
                    crow[n] = v;
                }
            }
        }
    }
}

// ---------------------------------------------------------------------------
// SRU elementwise scan with group-of-8 double-buffered register prefetch.
// One thread per (b,d) channel; only 1 wave/SIMD is possible (B*D=65536),
// so latency hiding is pure ILP: 32 loads in flight while computing 8 steps.
// U is the chunk buffer (row 0 == t0); h bf16 in place; carry fp32.
// ---------------------------------------------------------------------------
__global__ __launch_bounds__(256) void sru_scan(
    const float* __restrict__ U, __hip_bfloat16* __restrict__ h,
    const float* __restrict__ v, const float* __restrict__ bvec,
    float* __restrict__ carry, float* __restrict__ cfin,
    int t0, int t1)
{
    constexpr int G = 8;
    int idx = blockIdx.x * 256 + threadIdx.x;   // 0..B*D-1
    int d = idx & (D_ - 1);
    int b = idx >> 10;

    float vf = v[d],      vr = v[D_ + d];
    float bf = bvec[d],   br = bvec[D_ + d];
    float c = (t0 == 0) ? 0.f : carry[idx];

    const size_t su = (size_t)B_ * 3 * D_;
    const size_t sh = (size_t)B_ * D_;
    const float* Up = U + (size_t)b * (3 * D_) + d;     // chunk-local t=0
    __hip_bfloat16* hp = h + (size_t)t0 * sh + idx;

    const int nsteps  = t1 - t0;
    const int ngroups = nsteps / G;

    float a0[G], a1[G], a2[G], ax[G];   // buffer A
    float b0[G], b1v[G], b2[G], bx[G];  // buffer B

    auto load_into = [&](int g, float (&u0)[G], float (&u1)[G],
                         float (&u2)[G], float (&xt)[G]) {
        const float* Upn = Up + (size_t)g * G * su;
        const __hip_bfloat16* hpn = hp + (size_t)g * G * sh;
#pragma unroll
        for (int j = 0; j < G; ++j) {
            u0[j] = Upn[0];
            u1[j] = Upn[D_];
            u2[j] = Upn[2 * D_];
            xt[j] = __bfloat162float(*hpn);
            Upn += su; hpn += sh;
        }
    };
    auto compute = [&](int g, const float (&u0)[G], const float (&u1)[G],
                       const float (&u2)[G], const float (&xt)[G]) {
        __hip_bfloat16* hps = hp + (size_t)g * G * sh;
#pragma unroll
        for (int j = 0; j < G; ++j) {
            float f = 1.f / (1.f + __expf(-(u1[j] + vf * c + bf)));
            c = f * c + (1.f - f) * u0[j];
            float r = 1.f / (1.f + __expf(-(u2[j] + vr * c + br)));
            *hps = __float2bfloat16(r * c + (1.f - r) * xt[j]);
            hps += sh;
        }
    };

    if (ngroups > 0) {
        load_into(0, a0, a1, a2, ax);
        int g = 0;
        // process pairs: prefetch g+1 into B while computing A, and vice versa
        for (; g + 2 <= ngroups; g += 2) {
            load_into(g + 1, b0, b1v, b2, bx);
            compute(g, a0, a1, a2, ax);
            if (g + 2 < ngroups) load_into(g + 2, a0, a1, a2, ax);
            compute(g + 1, b0, b1v, b2, bx);
        }
        if (g < ngroups) compute(g, a0, a1, a2, ax);   // odd tail group
    }
    // scalar tail (nsteps % G)
    for (int t = ngroups * G; t < nsteps; ++t) {
        const float* Upn = Up + (size_t)t * su;
        float u0 = Upn[0], u1 = Upn[D_], u2 = Upn[2 * D_];
        __hip_bfloat16* hps = hp + (size_t)t * sh;
        float xv = __bfloat162float(*hps);
        float f = 1.f / (1.f + __expf(-(u1 + vf * c + bf)));
        c = f * c + (1.f - f) * u0;
        float r = 1.f / (1.f + __expf(-(u2 + vr * c + br)));
        *hps = __float2bfloat16(r * c + (1.f - r) * xv);
    }

    carry[idx] = c;
    if (cfin) cfin[idx] = c;
}

// ---------------------------------------------------------------------------
extern "C" void kernel_launch(void* const* d_in, const int* in_sizes, int n_in,
                              void* d_out, int out_size, void* d_ws, size_t ws_size,
                              hipStream_t stream)
{
    const float* x     = (const float*)d_in[0];
    const float* W1    = (const float*)d_in[2];
    const float* b1    = (const float*)d_in[3];
    const float* sru_W = (const float*)d_in[4];
    const float* sru_v = (const float*)d_in[5];
    const float* sru_b = (const float*)d_in[6];
    const float* W3    = (const float*)d_in[7];
    const float* b3    = (const float*)d_in[8];

    float* y    = (float*)d_out;                       // (B*T, O) batch-major
    float* cfin = y + (size_t)(B_ * T_) * O_;          // (L, B, D)

    // Workspace layout
    char* ws = (char*)d_ws;
    size_t off = 0;
    __hip_bfloat16* h = (__hip_bfloat16*)(ws + off);
    off += (size_t)T_ * B_ * D_ * sizeof(__hip_bfloat16);           // 64 MiB
    float* carry = (float*)(ws + off);
    off += (size_t)B_ * D_ * sizeof(float);
    __hip_bfloat16* Wt = (__hip_bfloat16*)(ws + off);               // L x (3D x D)
    off += (size_t)L_ * 3 * D_ * D_ * sizeof(__hip_bfloat16);
    __hip_bfloat16* Wt3 = (__hip_bfloat16*)(ws + off);              // OPAD x D
    off += (size_t)OPAD * D_ * sizeof(__hip_bfloat16);
    float* Ubuf = (float*)(ws + off);

    size_t perT  = (size_t)B_ * 3 * D_ * sizeof(float);             // 768 KiB / t
    size_t avail = (ws_size > off) ? ws_size - off : 0;
    // chunkT=128 -> Ubuf chunk = 100 MiB, L3-resident (U never hits HBM)
    int chunkT = (int)(avail / perT);
    if (chunkT > 128) chunkT = 128;
    chunkT &= ~7;                       // multiple of 8 (scan groups, M%128)
    if (chunkT < 2) chunkT = 2;

    // 0) weight transpose+cast (every call; no static state allowed)
    for (int l = 0; l < L_; ++l) {
        dim3 gt(D_ / 32, (3 * D_) / 32);
        transpose_cast<<<gt, 256, 0, stream>>>(
            sru_W + (size_t)l * D_ * 3 * D_, Wt + (size_t)l * 3 * D_ * D_,
            D_, 3 * D_, 3 * D_);
    }
    {
        dim3 gt(D_ / 32, OPAD / 32);
        transpose_cast<<<gt, 256, 0, stream>>>(W3, Wt3, D_, O_, OPAD);
    }

    // 1) FC1 -> h (bf16, time-major)
    fc1_kernel<<<(T_ * B_ * D_) / 256, 256, 0, stream>>>(x, W1, b1, h);

    // 2) SRU layers: chunked bulk U GEMM + elementwise scan (U stays in L3)
    for (int l = 0; l < L_; ++l) {
        const __hip_bfloat16* Wl = Wt + (size_t)l * 3 * D_ * D_;
        const float* vl = sru_v + (size_t)l * 2 * D_;
        const float* bl = sru_b + (size_t)l * 2 * D_;
        for (int t0 = 0; t0 < T_; t0 += chunkT) {
            int t1 = (t0 + chunkT > T_) ? T_ : (t0 + chunkT);
            int rows = (t1 - t0) * B_;
            dim3 g((3 * D_) / 128, rows / 128);
            mfma_gemm<false, false><<<g, 256, 0, stream>>>(
                h + (size_t)t0 * B_ * D_, Wl, Ubuf,
                D_, 3 * D_, 3 * D_, nullptr);
            sru_scan<<<(B_ * D_) / 256, 256, 0, stream>>>(
                Ubuf, h, vl, bl, carry,
                (t1 == T_) ? (cfin + (size_t)l * B_ * D_) : nullptr,
                t0, t1);
        }
    }

    // 3) Final: y[b*T+t, :] = h[t*B+b, :] @ W3 + b3  (N guarded, remap)
    dim3 gf(OPAD / 128, (B_ * T_) / 128);
    mfma_gemm<true, true><<<gf, 256, 0, stream>>>(
        h, Wt3, y, D_, O_, O_, b3);
}

// Round 4
// 1538.784 us; speedup vs baseline: 6.6569x; 1.1844x over previous
//
#include <hip/hip_runtime.h>
#include <hip/hip_bf16.h>

// Problem constants (B,T,F,D,O,L) = (64, 512, 20, 1024, 1095, 3)
#define B_ 64
#define T_ 512
#define F_ 20
#define D_ 1024
#define O_ 1095
#define L_ 3
#define OPAD 1152   // O_ padded to multiple of 128 for the MFMA tile

typedef __attribute__((ext_vector_type(8))) short bf16x8;   // 8 bf16 = 4 VGPRs
typedef __attribute__((ext_vector_type(4))) float f32x4;

// async global->LDS, 16 bytes/lane. LDS dst must be wave-uniform base;
// HW writes base + lane*16 (guide §5 caveat).
__device__ __forceinline__ void async16(const void* g, void* l) {
    __builtin_amdgcn_global_load_lds(
        (const __attribute__((address_space(1))) unsigned int*)g,
        (__attribute__((address_space(3))) unsigned int*)l, 16, 0, 0);
}

// ---------------------------------------------------------------------------
// FC1: h[t*B+b, d] = sum_f x[b,t,f] * W1[f,d] + b1[d]  -> bf16, time-major
// Block = 256 threads, covers one t (64 rows = all b), full D.
// Thread owns 4 d-columns: W1 slice (20x4) register-resident; x staged in LDS.
// ---------------------------------------------------------------------------
__global__ __launch_bounds__(256) void fc1_kernel(
    const float* __restrict__ x, const float* __restrict__ W1,
    const float* __restrict__ b1, __hip_bfloat16* __restrict__ h)
{
    __shared__ float xs[64][F_];          // 5 KB, reads are broadcast
    const int tid = threadIdx.x;
    const int d4  = tid * 4;              // 256 threads x 4 = 1024 = D
    const int r0  = blockIdx.x * 64;      // row base (m = t*B+b); t const, b=r
    const int t   = r0 >> 6;

    // stage x rows: b = r, x[b][t][f]
    for (int i = tid; i < 64 * F_; i += 256) {
        int r = i / F_, f = i - r * F_;
        xs[r][f] = x[((size_t)r * T_ + t) * F_ + f];
    }

    // W1 slice into registers (20 x float4)
    float4 w[F_];
#pragma unroll
    for (int f = 0; f < F_; ++f)
        w[f] = *(const float4*)(W1 + (size_t)f * D_ + d4);
    float4 bias = *(const float4*)(b1 + d4);

    __syncthreads();

    for (int r = 0; r < 64; ++r) {
        float a0 = bias.x, a1 = bias.y, a2 = bias.z, a3 = bias.w;
#pragma unroll
        for (int f = 0; f < F_; ++f) {
            float xv = xs[r][f];
            a0 = fmaf(xv, w[f].x, a0);
            a1 = fmaf(xv, w[f].y, a1);
            a2 = fmaf(xv, w[f].z, a2);
            a3 = fmaf(xv, w[f].w, a3);
        }
        union { __hip_bfloat162 h2[2]; float2 f2; } o;
        o.h2[0] = __float22bfloat162_rn(float2{a0, a1});
        o.h2[1] = __float22bfloat162_rn(float2{a2, a3});
        *(float2*)(h + ((size_t)(r0 + r) << 10) + d4) = o.f2;
    }
}

// ---------------------------------------------------------------------------
// Tiled transpose+cast: in fp32 (K x N) -> out bf16 (Npad x K), zero-pad rows
// ---------------------------------------------------------------------------
__global__ __launch_bounds__(256) void transpose_cast(
    const float* __restrict__ in, __hip_bfloat16* __restrict__ out,
    int K, int N, int Npad)
{
    __shared__ float tile[32][33];
    int k0 = blockIdx.x * 32;
    int n0 = blockIdx.y * 32;
    int tx = threadIdx.x & 31, ty = threadIdx.x >> 5;   // ty 0..7
#pragma unroll
    for (int r = 0; r < 4; ++r) {
        int n = n0 + tx;
        int k = k0 + ty + r * 8;
        tile[ty + r * 8][tx] = (n < N) ? in[(size_t)k * N + n] : 0.f;
    }
    __syncthreads();
#pragma unroll
    for (int r = 0; r < 4; ++r) {
        int nn = n0 + ty + r * 8;
        out[(size_t)nn * K + k0 + tx] = __float2bfloat16(tile[tx][ty + r * 8]);
    }
}

// ---------------------------------------------------------------------------
// m97-style MFMA GEMM: C[M,N] = A[M,K] @ Bt[N,K]^T  (bf16 in)
// 128x128 tile, BK=32, 256 threads (4 waves, 2x2 wave grid, 4x4 MFMA each).
// OUT_BF16: store bf16 (layer U). Else fp32 (+bias, +remap, +N guard).
// ---------------------------------------------------------------------------
template<bool GUARD_N, bool REMAP, bool OUT_BF16>
__global__ __launch_bounds__(256) void mfma_gemm(
    const __hip_bfloat16* __restrict__ A,
    const __hip_bfloat16* __restrict__ Bt,
    void* __restrict__ Cv,
    int K, int ldc, int Nreal,
    const float* __restrict__ bias)
{
    __shared__ __align__(16) char smem[16384];
    char* As = smem;            // 128 rows x 32 k x bf16 = 8192 B
    char* Bs = smem + 8192;

    const int tid  = threadIdx.x;
    const int lane = tid & 63;
    const int w    = tid >> 6;

    const int tileM = blockIdx.y * 128;
    const int tileN = blockIdx.x * 128;

    const int r0 = tid >> 2, c0 = (tid & 3) * 8;
    const __hip_bfloat16* pA0 = A  + (size_t)(tileM + r0) * K + c0;
    const __hip_bfloat16* pA1 = A  + (size_t)(tileM + r0 + 64) * K + c0;
    const __hip_bfloat16* pB0 = Bt + (size_t)(tileN + r0) * K + c0;
    const __hip_bfloat16* pB1 = Bt + (size_t)(tileN + r0 + 64) * K + c0;

    const int wb = w * 1024;    // wave-uniform LDS byte offset

    const int wm = (w & 1) * 64;
    const int wn = (w >> 1) * 64;
    const int lr = lane & 15;
    const int lkB = (lane >> 4) * 16;

    f32x4 acc[4][4] = {};

    for (int k0 = 0; k0 < K; k0 += 32) {
        async16(pA0, As + wb);
        async16(pA1, As + 4096 + wb);
        async16(pB0, Bs + wb);
        async16(pB1, Bs + 4096 + wb);
        pA0 += 32; pA1 += 32; pB0 += 32; pB1 += 32;
        __syncthreads();

        bf16x8 a_frag[4], b_frag[4];
#pragma unroll
        for (int i = 0; i < 4; ++i)
            a_frag[i] = *(const bf16x8*)(As + (wm + i * 16 + lr) * 64 + lkB);
#pragma unroll
        for (int j = 0; j < 4; ++j)
            b_frag[j] = *(const bf16x8*)(Bs + (wn + j * 16 + lr) * 64 + lkB);

#pragma unroll
        for (int i = 0; i < 4; ++i)
#pragma unroll
            for (int j = 0; j < 4; ++j)
                acc[i][j] = __builtin_amdgcn_mfma_f32_16x16x32_bf16(
                    a_frag[i], b_frag[j], acc[i][j], 0, 0, 0);
        __syncthreads();
    }

    const int rquad = (lane >> 4) * 4;
#pragma unroll
    for (int i = 0; i < 4; ++i) {
#pragma unroll
        for (int r = 0; r < 4; ++r) {
            int m = tileM + wm + i * 16 + rquad + r;
            size_t orow = REMAP ? ((size_t)(m & (B_ - 1)) * T_ + (m >> 6)) : (size_t)m;
#pragma unroll
            for (int j = 0; j < 4; ++j) {
                int n = tileN + wn + j * 16 + lr;
                if (!GUARD_N || n < Nreal) {
                    float v = acc[i][j][r];
                    if (bias) v += bias[n];
                    if (OUT_BF16)
                        ((__hip_bfloat16*)Cv)[orow * ldc + n] = __float2bfloat16(v);
                    else
                        ((float*)Cv)[orow * ldc + n] = v;
                }
            }
        }
    }
}

// ---------------------------------------------------------------------------
// SRU elementwise scan, group-of-16 double-buffered register prefetch.
// One thread per (b,d); 1 wave/SIMD max (B*D=65536) -> latency hiding is ILP.
// U is bf16 chunk buffer (row 0 == t0); h bf16 in place; carry fp32.
// ---------------------------------------------------------------------------
__global__ __launch_bounds__(256) void sru_scan(
    const __hip_bfloat16* __restrict__ U, __hip_bfloat16* __restrict__ h,
    const float* __restrict__ v, const float* __restrict__ bvec,
    float* __restrict__ carry, float* __restrict__ cfin,
    int t0, int t1)
{
    constexpr int G = 16;
    int idx = blockIdx.x * 256 + threadIdx.x;   // 0..B*D-1
    int d = idx & (D_ - 1);
    int b = idx >> 10;

    float vf = v[d],      vr = v[D_ + d];
    float bf = bvec[d],   br = bvec[D_ + d];
    float c = (t0 == 0) ? 0.f : carry[idx];

    const size_t su = (size_t)B_ * 3 * D_;
    const size_t sh = (size_t)B_ * D_;
    const __hip_bfloat16* Up = U + (size_t)b * (3 * D_) + d;   // chunk-local t=0
    __hip_bfloat16* hp = h + (size_t)t0 * sh + idx;

    const int nsteps  = t1 - t0;
    const int ngroups = nsteps / G;

    float a0[G], a1[G], a2[G], ax[G];   // buffer A
    float b0[G], b1v[G], b2[G], bx[G];  // buffer B

    auto load_into = [&](int g, float (&u0)[G], float (&u1)[G],
                         float (&u2)[G], float (&xt)[G]) {
        const __hip_bfloat16* Upn = Up + (size_t)g * G * su;
        const __hip_bfloat16* hpn = hp + (size_t)g * G * sh;
#pragma unroll
        for (int j = 0; j < G; ++j) {
            u0[j] = __bfloat162float(Upn[0]);
            u1[j] = __bfloat162float(Upn[D_]);
            u2[j] = __bfloat162float(Upn[2 * D_]);
            xt[j] = __bfloat162float(*hpn);
            Upn += su; hpn += sh;
        }
    };
    auto compute = [&](int g, const float (&u0)[G], const float (&u1)[G],
                       const float (&u2)[G], const float (&xt)[G]) {
        __hip_bfloat16* hps = hp + (size_t)g * G * sh;
#pragma unroll
        for (int j = 0; j < G; ++j) {
            float f = 1.f / (1.f + __expf(-(u1[j] + vf * c + bf)));
            c = f * c + (1.f - f) * u0[j];
            float r = 1.f / (1.f + __expf(-(u2[j] + vr * c + br)));
            *hps = __float2bfloat16(r * c + (1.f - r) * xt[j]);
            hps += sh;
        }
    };

    if (ngroups > 0) {
        load_into(0, a0, a1, a2, ax);
        int g = 0;
        for (; g + 2 <= ngroups; g += 2) {
            load_into(g + 1, b0, b1v, b2, bx);
            compute(g, a0, a1, a2, ax);
            if (g + 2 < ngroups) load_into(g + 2, a0, a1, a2, ax);
            compute(g + 1, b0, b1v, b2, bx);
        }
        if (g < ngroups) compute(g, a0, a1, a2, ax);   // odd tail group
    }
    // scalar tail (nsteps % G)
    for (int t = ngroups * G; t < nsteps; ++t) {
        const __hip_bfloat16* Upn = Up + (size_t)t * su;
        float u0 = __bfloat162float(Upn[0]);
        float u1 = __bfloat162float(Upn[D_]);
        float u2 = __bfloat162float(Upn[2 * D_]);
        __hip_bfloat16* hps = hp + (size_t)t * sh;
        float xv = __bfloat162float(*hps);
        float f = 1.f / (1.f + __expf(-(u1 + vf * c + bf)));
        c = f * c + (1.f - f) * u0;
        float r = 1.f / (1.f + __expf(-(u2 + vr * c + br)));
        *hps = __float2bfloat16(r * c + (1.f - r) * xv);
    }

    carry[idx] = c;
    if (cfin) cfin[idx] = c;
}

// ---------------------------------------------------------------------------
extern "C" void kernel_launch(void* const* d_in, const int* in_sizes, int n_in,
                              void* d_out, int out_size, void* d_ws, size_t ws_size,
                              hipStream_t stream)
{
    const float* x     = (const float*)d_in[0];
    const float* W1    = (const float*)d_in[2];
    const float* b1    = (const float*)d_in[3];
    const float* sru_W = (const float*)d_in[4];
    const float* sru_v = (const float*)d_in[5];
    const float* sru_b = (const float*)d_in[6];
    const float* W3    = (const float*)d_in[7];
    const float* b3    = (const float*)d_in[8];

    float* y    = (float*)d_out;                       // (B*T, O) batch-major
    float* cfin = y + (size_t)(B_ * T_) * O_;          // (L, B, D)

    // Workspace layout
    char* ws = (char*)d_ws;
    size_t off = 0;
    __hip_bfloat16* h = (__hip_bfloat16*)(ws + off);
    off += (size_t)T_ * B_ * D_ * sizeof(__hip_bfloat16);           // 64 MiB
    float* carry = (float*)(ws + off);
    off += (size_t)B_ * D_ * sizeof(float);
    __hip_bfloat16* Wt = (__hip_bfloat16*)(ws + off);               // L x (3D x D)
    off += (size_t)L_ * 3 * D_ * D_ * sizeof(__hip_bfloat16);
    __hip_bfloat16* Wt3 = (__hip_bfloat16*)(ws + off);              // OPAD x D
    off += (size_t)OPAD * D_ * sizeof(__hip_bfloat16);
    __hip_bfloat16* Ubuf = (__hip_bfloat16*)(ws + off);

    size_t perT  = (size_t)B_ * 3 * D_ * sizeof(__hip_bfloat16);    // 384 KiB / t
    size_t avail = (ws_size > off) ? ws_size - off : 0;
    // chunkT=128 -> Ubuf chunk = 50 MiB, L3-resident
    int chunkT = (int)(avail / perT);
    if (chunkT > 128) chunkT = 128;
    chunkT &= ~15;                      // multiple of 16 (scan groups, M%128)
    if (chunkT < 2) chunkT = 2;

    // 0) weight transpose+cast (every call; no static state allowed)
    for (int l = 0; l < L_; ++l) {
        dim3 gt(D_ / 32, (3 * D_) / 32);
        transpose_cast<<<gt, 256, 0, stream>>>(
            sru_W + (size_t)l * D_ * 3 * D_, Wt + (size_t)l * 3 * D_ * D_,
            D_, 3 * D_, 3 * D_);
    }
    {
        dim3 gt(D_ / 32, OPAD / 32);
        transpose_cast<<<gt, 256, 0, stream>>>(W3, Wt3, D_, O_, OPAD);
    }

    // 1) FC1 -> h (bf16, time-major)
    fc1_kernel<<<(T_ * B_) / 64, 256, 0, stream>>>(x, W1, b1, h);

    // 2) SRU layers: chunked bulk U GEMM (bf16 out) + elementwise scan
    for (int l = 0; l < L_; ++l) {
        const __hip_bfloat16* Wl = Wt + (size_t)l * 3 * D_ * D_;
        const float* vl = sru_v + (size_t)l * 2 * D_;
        const float* bl = sru_b + (size_t)l * 2 * D_;
        for (int t0 = 0; t0 < T_; t0 += chunkT) {
            int t1 = (t0 + chunkT > T_) ? T_ : (t0 + chunkT);
            int rows = (t1 - t0) * B_;
            dim3 g((3 * D_) / 128, rows / 128);
            mfma_gemm<false, false, true><<<g, 256, 0, stream>>>(
                h + (size_t)t0 * B_ * D_, Wl, Ubuf,
                D_, 3 * D_, 3 * D_, nullptr);
            sru_scan<<<(B_ * D_) / 256, 256, 0, stream>>>(
                Ubuf, h, vl, bl, carry,
                (t1 == T_) ? (cfin + (size_t)l * B_ * D_) : nullptr,
                t0, t1);
        }
    }

    // 3) Final: y[b*T+t, :] = h[t*B+b, :] @ W3 + b3  (fp32 out, guarded, remap)
    dim3 gf(OPAD / 128, (B_ * T_) / 128);
    mfma_gemm<true, true, false><<<gf, 256, 0, stream>>>(
        h, Wt3, y, D_, O_, O_, b3);
}

// Round 5
// 1478.036 us; speedup vs baseline: 6.9305x; 1.0411x over previous
//
#include <hip/hip_runtime.h>
#include <hip/hip_bf16.h>

// Problem constants (B,T,F,D,O,L) = (64, 512, 20, 1024, 1095, 3)
#define B_ 64
#define T_ 512
#define F_ 20
#define D_ 1024
#define O_ 1095
#define L_ 3
#define OPAD 1152   // O_ padded to multiple of 128 for the MFMA tile

typedef __attribute__((ext_vector_type(8))) short bf16x8;   // 8 bf16 = 4 VGPRs
typedef __attribute__((ext_vector_type(4))) float f32x4;

// async global->LDS, 16 bytes/lane. LDS dst must be wave-uniform base;
// HW writes base + lane*16 (guide §5 caveat).
__device__ __forceinline__ void async16(const void* g, void* l) {
    __builtin_amdgcn_global_load_lds(
        (const __attribute__((address_space(1))) unsigned int*)g,
        (__attribute__((address_space(3))) unsigned int*)l, 16, 0, 0);
}

// ---------------------------------------------------------------------------
// FC1: h[t*B+b, d] = sum_f x[b,t,f] * W1[f,d] + b1[d]  -> bf16, time-major
// ---------------------------------------------------------------------------
__global__ __launch_bounds__(256) void fc1_kernel(
    const float* __restrict__ x, const float* __restrict__ W1,
    const float* __restrict__ b1, __hip_bfloat16* __restrict__ h)
{
    __shared__ float xs[64][F_];          // 5 KB, reads are broadcast
    const int tid = threadIdx.x;
    const int d4  = tid * 4;              // 256 threads x 4 = 1024 = D
    const int r0  = blockIdx.x * 64;      // row base (m = t*B+b); t const, b=r
    const int t   = r0 >> 6;

    for (int i = tid; i < 64 * F_; i += 256) {
        int r = i / F_, f = i - r * F_;
        xs[r][f] = x[((size_t)r * T_ + t) * F_ + f];
    }

    float4 w[F_];
#pragma unroll
    for (int f = 0; f < F_; ++f)
        w[f] = *(const float4*)(W1 + (size_t)f * D_ + d4);
    float4 bias = *(const float4*)(b1 + d4);

    __syncthreads();

    for (int r = 0; r < 64; ++r) {
        float a0 = bias.x, a1 = bias.y, a2 = bias.z, a3 = bias.w;
#pragma unroll
        for (int f = 0; f < F_; ++f) {
            float xv = xs[r][f];
            a0 = fmaf(xv, w[f].x, a0);
            a1 = fmaf(xv, w[f].y, a1);
            a2 = fmaf(xv, w[f].z, a2);
            a3 = fmaf(xv, w[f].w, a3);
        }
        union { __hip_bfloat162 h2[2]; float2 f2; } o;
        o.h2[0] = __float22bfloat162_rn(float2{a0, a1});
        o.h2[1] = __float22bfloat162_rn(float2{a2, a3});
        *(float2*)(h + ((size_t)(r0 + r) << 10) + d4) = o.f2;
    }
}

// ---------------------------------------------------------------------------
// Tiled transpose+cast: in fp32 (K x N) -> out bf16 (Npad x K), zero-pad rows
// ---------------------------------------------------------------------------
__global__ __launch_bounds__(256) void transpose_cast(
    const float* __restrict__ in, __hip_bfloat16* __restrict__ out,
    int K, int N, int Npad)
{
    __shared__ float tile[32][33];
    int k0 = blockIdx.x * 32;
    int n0 = blockIdx.y * 32;
    int tx = threadIdx.x & 31, ty = threadIdx.x >> 5;   // ty 0..7
#pragma unroll
    for (int r = 0; r < 4; ++r) {
        int n = n0 + tx;
        int k = k0 + ty + r * 8;
        tile[ty + r * 8][tx] = (n < N) ? in[(size_t)k * N + n] : 0.f;
    }
    __syncthreads();
#pragma unroll
    for (int r = 0; r < 4; ++r) {
        int nn = n0 + ty + r * 8;
        out[(size_t)nn * K + k0 + tx] = __float2bfloat16(tile[tx][ty + r * 8]);
    }
}

// ---------------------------------------------------------------------------
// m97-style MFMA GEMM: C[M,N] = A[M,K] @ Bt[N,K]^T  (bf16 in)
// 128x128 tile, BK=32, 256 threads (4 waves, 2x2 wave grid, 4x4 MFMA each).
// 1-D grid + XCD swizzle: blocks with the same M-tile get lid%8 == const so
// they land on one XCD (round-robin dispatch) -> A-tile stays in its L2.
// Requires nTilesM % 8 == 0.
// Epilogue repacks through LDS for row-contiguous full-line stores.
// OUT_BF16: bf16 store (layer U). Else fp32 (+bias, +remap, +N guard).
// ---------------------------------------------------------------------------
template<bool GUARD_N, bool REMAP, bool OUT_BF16>
__global__ __launch_bounds__(256) void mfma_gemm(
    const __hip_bfloat16* __restrict__ A,
    const __hip_bfloat16* __restrict__ Bt,
    void* __restrict__ Cv,
    int K, int ldc, int Nreal,
    const float* __restrict__ bias, int nTilesN)
{
    // 16384 B for K-loop staging; epilogue reuses the region (36864 B total):
    //   bf16 repack: 4 waves x 64 rows x 72 (pad) x 2 B = 36864
    //   fp32 repack: 4 waves x 32 rows x 68 (pad) x 4 B = 34816
    __shared__ __align__(16) char smem[36864];
    char* As = smem;            // 128 rows x 32 k x bf16 = 8192 B
    char* Bs = smem + 8192;

    const int tid  = threadIdx.x;
    const int lane = tid & 63;
    const int w    = tid >> 6;

    // swizzle: lid = (by&7) + 8*(bx + nTilesN*(by>>3))
    const int lid = blockIdx.x;
    const int c8  = lid & 7;
    const int xq  = lid >> 3;
    const int bx  = xq % nTilesN;
    const int by  = (xq / nTilesN) * 8 + c8;

    const int tileM = by * 128;
    const int tileN = bx * 128;

    const int r0 = tid >> 2, c0 = (tid & 3) * 8;
    const __hip_bfloat16* pA0 = A  + (size_t)(tileM + r0) * K + c0;
    const __hip_bfloat16* pA1 = A  + (size_t)(tileM + r0 + 64) * K + c0;
    const __hip_bfloat16* pB0 = Bt + (size_t)(tileN + r0) * K + c0;
    const __hip_bfloat16* pB1 = Bt + (size_t)(tileN + r0 + 64) * K + c0;

    const int wb = w * 1024;    // wave-uniform LDS byte offset

    const int wm = (w & 1) * 64;
    const int wn = (w >> 1) * 64;
    const int lr = lane & 15;
    const int lkB = (lane >> 4) * 16;

    f32x4 acc[4][4] = {};

    for (int k0 = 0; k0 < K; k0 += 32) {
        async16(pA0, As + wb);
        async16(pA1, As + 4096 + wb);
        async16(pB0, Bs + wb);
        async16(pB1, Bs + 4096 + wb);
        pA0 += 32; pA1 += 32; pB0 += 32; pB1 += 32;
        __syncthreads();

        bf16x8 a_frag[4], b_frag[4];
#pragma unroll
        for (int i = 0; i < 4; ++i)
            a_frag[i] = *(const bf16x8*)(As + (wm + i * 16 + lr) * 64 + lkB);
#pragma unroll
        for (int j = 0; j < 4; ++j)
            b_frag[j] = *(const bf16x8*)(Bs + (wn + j * 16 + lr) * 64 + lkB);

#pragma unroll
        for (int i = 0; i < 4; ++i)
#pragma unroll
            for (int j = 0; j < 4; ++j)
                acc[i][j] = __builtin_amdgcn_mfma_f32_16x16x32_bf16(
                    a_frag[i], b_frag[j], acc[i][j], 0, 0, 0);
        __syncthreads();   // also licenses epilogue reuse of As/Bs region
    }

    const int rquad = (lane >> 4) * 4;

    if (OUT_BF16) {
        // ---- bf16 repack epilogue: rows padded to 72 elems (144 B:
        //      16-B aligned, bank-rotated). Wave-private region.
        __hip_bfloat16* stg = (__hip_bfloat16*)smem + (size_t)w * 4608;
#pragma unroll
        for (int i = 0; i < 4; ++i)
#pragma unroll
            for (int r = 0; r < 4; ++r) {
                int row = i * 16 + rquad + r;
#pragma unroll
                for (int j = 0; j < 4; ++j)
                    stg[row * 72 + j * 16 + lr] = __float2bfloat16(acc[i][j][r]);
            }
        __syncthreads();
        __hip_bfloat16* Cb = (__hip_bfloat16*)Cv;
#pragma unroll
        for (int rr = 0; rr < 8; ++rr) {
            int row  = rr * 8 + (lane >> 3);
            int colb = (lane & 7) * 8;
            bf16x8 vdat = *(const bf16x8*)(stg + row * 72 + colb);
            int m = tileM + wm + row;
            int n = tileN + wn + colb;
            size_t orow = REMAP ? ((size_t)(m & (B_ - 1)) * T_ + (m >> 6)) : (size_t)m;
            *(bf16x8*)(Cb + orow * ldc + n) = vdat;   // 8 rows x 128 B / inst
        }
    } else {
        // ---- fp32 repack epilogue in two 32-row halves: rows padded to 68
        //      floats (272 B). Scalar dword stores (ldc may be odd) but each
        //      inst covers a contiguous 256-B row segment.
        float* stgf = (float*)smem + (size_t)w * 2176;
        float* Cf = (float*)Cv;
#pragma unroll
        for (int half = 0; half < 2; ++half) {
            __syncthreads();
#pragma unroll
            for (int ii = 0; ii < 2; ++ii) {
                int i = half * 2 + ii;
#pragma unroll
                for (int r = 0; r < 4; ++r) {
                    int row = ii * 16 + rquad + r;   // 0..31
#pragma unroll
                    for (int j = 0; j < 4; ++j) {
                        int n = tileN + wn + j * 16 + lr;
                        float v = acc[i][j][r];
                        if (bias) v += bias[n];
                        stgf[row * 68 + j * 16 + lr] = v;
                    }
                }
            }
            __syncthreads();
            // read back: 64 lanes = one 64-col row slice (256 B) per inst
            for (int row = 0; row < 32; ++row) {
                float vdat = stgf[row * 68 + lane];
                int m = tileM + wm + half * 32 + row;
                int n = tileN + wn + lane;
                size_t orow = REMAP ? ((size_t)(m & (B_ - 1)) * T_ + (m >> 6)) : (size_t)m;
                if (!GUARD_N || n < Nreal)
                    Cf[orow * ldc + n] = vdat;
            }
        }
    }
}

// ---------------------------------------------------------------------------
// SRU elementwise scan, group-of-16 double-buffered register prefetch.
// One thread per (b,d); 1 wave/SIMD max (B*D=65536) -> latency hiding is ILP.
// U is bf16 chunk buffer (row 0 == t0); h bf16 in place; carry fp32.
// ---------------------------------------------------------------------------
__global__ __launch_bounds__(256) void sru_scan(
    const __hip_bfloat16* __restrict__ U, __hip_bfloat16* __restrict__ h,
    const float* __restrict__ v, const float* __restrict__ bvec,
    float* __restrict__ carry, float* __restrict__ cfin,
    int t0, int t1)
{
    constexpr int G = 16;
    int idx = blockIdx.x * 256 + threadIdx.x;   // 0..B*D-1
    int d = idx & (D_ - 1);
    int b = idx >> 10;

    float vf = v[d],      vr = v[D_ + d];
    float bf = bvec[d],   br = bvec[D_ + d];
    float c = (t0 == 0) ? 0.f : carry[idx];

    const size_t su = (size_t)B_ * 3 * D_;
    const size_t sh = (size_t)B_ * D_;
    const __hip_bfloat16* Up = U + (size_t)b * (3 * D_) + d;   // chunk-local t=0
    __hip_bfloat16* hp = h + (size_t)t0 * sh + idx;

    const int nsteps  = t1 - t0;
    const int ngroups = nsteps / G;

    float a0[G], a1[G], a2[G], ax[G];   // buffer A
    float b0[G], b1v[G], b2[G], bx[G];  // buffer B

    auto load_into = [&](int g, float (&u0)[G], float (&u1)[G],
                         float (&u2)[G], float (&xt)[G]) {
        const __hip_bfloat16* Upn = Up + (size_t)g * G * su;
        const __hip_bfloat16* hpn = hp + (size_t)g * G * sh;
#pragma unroll
        for (int j = 0; j < G; ++j) {
            u0[j] = __bfloat162float(Upn[0]);
            u1[j] = __bfloat162float(Upn[D_]);
            u2[j] = __bfloat162float(Upn[2 * D_]);
            xt[j] = __bfloat162float(*hpn);
            Upn += su; hpn += sh;
        }
    };
    auto compute = [&](int g, const float (&u0)[G], const float (&u1)[G],
                       const float (&u2)[G], const float (&xt)[G]) {
        __hip_bfloat16* hps = hp + (size_t)g * G * sh;
#pragma unroll
        for (int j = 0; j < G; ++j) {
            float f = 1.f / (1.f + __expf(-(u1[j] + vf * c + bf)));
            c = f * c + (1.f - f) * u0[j];
            float r = 1.f / (1.f + __expf(-(u2[j] + vr * c + br)));
            *hps = __float2bfloat16(r * c + (1.f - r) * xt[j]);
            hps += sh;
        }
    };

    if (ngroups > 0) {
        load_into(0, a0, a1, a2, ax);
        int g = 0;
        for (; g + 2 <= ngroups; g += 2) {
            load_into(g + 1, b0, b1v, b2, bx);
            compute(g, a0, a1, a2, ax);
            if (g + 2 < ngroups) load_into(g + 2, a0, a1, a2, ax);
            compute(g + 1, b0, b1v, b2, bx);
        }
        if (g < ngroups) compute(g, a0, a1, a2, ax);   // odd tail group
    }
    for (int t = ngroups * G; t < nsteps; ++t) {
        const __hip_bfloat16* Upn = Up + (size_t)t * su;
        float u0 = __bfloat162float(Upn[0]);
        float u1 = __bfloat162float(Upn[D_]);
        float u2 = __bfloat162float(Upn[2 * D_]);
        __hip_bfloat16* hps = hp + (size_t)t * sh;
        float xv = __bfloat162float(*hps);
        float f = 1.f / (1.f + __expf(-(u1 + vf * c + bf)));
        c = f * c + (1.f - f) * u0;
        float r = 1.f / (1.f + __expf(-(u2 + vr * c + br)));
        *hps = __float2bfloat16(r * c + (1.f - r) * xv);
    }

    carry[idx] = c;
    if (cfin) cfin[idx] = c;
}

// ---------------------------------------------------------------------------
extern "C" void kernel_launch(void* const* d_in, const int* in_sizes, int n_in,
                              void* d_out, int out_size, void* d_ws, size_t ws_size,
                              hipStream_t stream)
{
    const float* x     = (const float*)d_in[0];
    const float* W1    = (const float*)d_in[2];
    const float* b1    = (const float*)d_in[3];
    const float* sru_W = (const float*)d_in[4];
    const float* sru_v = (const float*)d_in[5];
    const float* sru_b = (const float*)d_in[6];
    const float* W3    = (const float*)d_in[7];
    const float* b3    = (const float*)d_in[8];

    float* y    = (float*)d_out;                       // (B*T, O) batch-major
    float* cfin = y + (size_t)(B_ * T_) * O_;          // (L, B, D)

    // Workspace layout
    char* ws = (char*)d_ws;
    size_t off = 0;
    __hip_bfloat16* h = (__hip_bfloat16*)(ws + off);
    off += (size_t)T_ * B_ * D_ * sizeof(__hip_bfloat16);           // 64 MiB
    float* carry = (float*)(ws + off);
    off += (size_t)B_ * D_ * sizeof(float);
    __hip_bfloat16* Wt = (__hip_bfloat16*)(ws + off);               // L x (3D x D)
    off += (size_t)L_ * 3 * D_ * D_ * sizeof(__hip_bfloat16);
    __hip_bfloat16* Wt3 = (__hip_bfloat16*)(ws + off);              // OPAD x D
    off += (size_t)OPAD * D_ * sizeof(__hip_bfloat16);
    __hip_bfloat16* Ubuf = (__hip_bfloat16*)(ws + off);

    size_t perT  = (size_t)B_ * 3 * D_ * sizeof(__hip_bfloat16);    // 384 KiB / t
    size_t avail = (ws_size > off) ? ws_size - off : 0;
    // chunkT=128 -> Ubuf chunk = 50 MiB, L3-resident
    int chunkT = (int)(avail / perT);
    if (chunkT > 128) chunkT = 128;
    chunkT &= ~15;                      // mult of 16 (scan groups; 8 M-tiles)
    if (chunkT < 16) chunkT = 16;

    // 0) weight transpose+cast (every call; no static state allowed)
    for (int l = 0; l < L_; ++l) {
        dim3 gt(D_ / 32, (3 * D_) / 32);
        transpose_cast<<<gt, 256, 0, stream>>>(
            sru_W + (size_t)l * D_ * 3 * D_, Wt + (size_t)l * 3 * D_ * D_,
            D_, 3 * D_, 3 * D_);
    }
    {
        dim3 gt(D_ / 32, OPAD / 32);
        transpose_cast<<<gt, 256, 0, stream>>>(W3, Wt3, D_, O_, OPAD);
    }

    // 1) FC1 -> h (bf16, time-major)
    fc1_kernel<<<(T_ * B_) / 64, 256, 0, stream>>>(x, W1, b1, h);

    // 2) SRU layers: chunked bulk U GEMM (bf16 out) + elementwise scan
    for (int l = 0; l < L_; ++l) {
        const __hip_bfloat16* Wl = Wt + (size_t)l * 3 * D_ * D_;
        const float* vl = sru_v + (size_t)l * 2 * D_;
        const float* bl = sru_b + (size_t)l * 2 * D_;
        for (int t0 = 0; t0 < T_; t0 += chunkT) {
            int t1 = (t0 + chunkT > T_) ? T_ : (t0 + chunkT);
            int rows = (t1 - t0) * B_;
            int nTilesN = (3 * D_) / 128;            // 24
            int nblocks = (rows / 128) * nTilesN;
            mfma_gemm<false, false, true><<<nblocks, 256, 0, stream>>>(
                h + (size_t)t0 * B_ * D_, Wl, Ubuf,
                D_, 3 * D_, 3 * D_, nullptr, nTilesN);
            sru_scan<<<(B_ * D_) / 256, 256, 0, stream>>>(
                Ubuf, h, vl, bl, carry,
                (t1 == T_) ? (cfin + (size_t)l * B_ * D_) : nullptr,
                t0, t1);
        }
    }

    // 3) Final: y[b*T+t, :] = h[t*B+b, :] @ W3 + b3  (fp32 out, guarded, remap)
    {
        int nTilesN = OPAD / 128;                    // 9
        int nblocks = ((B_ * T_) / 128) * nTilesN;   // 256 * 9
        mfma_gemm<true, true, false><<<nblocks, 256, 0, stream>>>(
            h, Wt3, y, D_, O_, O_, b3, nTilesN);
    }
}